// Round 1
// baseline (404.499 us; speedup 1.0000x reference)
//
#include <hip/hip_runtime.h>

// OuterProductMean: C[b] = A[b]^T @ B[b] / S
// A,B: (32, 4096, 256) fp32 ; C: (32, 256, 256) fp32
//
// Strategy: bf16 hi/lo split (x = hi + lo) -> 3 MFMAs (hh, hl, lh) per tile,
// ~2^-16 rel accuracy at bf16-MFMA rate -> memory-bound (268MB / 6.3TB/s ~ 43us).
// Grid 32 batches x 8 K-chunks = 256 blocks (1/CU), 1024 thr (16 waves).
// Each block: full 256x256 output over S-chunk 512, atomicAdd epilogue.
// Reg-staged transpose: global fp32 [s][m] -> LDS bf16 [m][s] hi/lo, XOR-swizzled.
// 2-phase pipeline, raw s_barrier + manual lgkmcnt, RA/RB reg double-buffer.

typedef __attribute__((ext_vector_type(8))) short bf16x8;
typedef __attribute__((ext_vector_type(4))) float f32x4;
typedef __attribute__((ext_vector_type(4))) float fvec4;

#define SEQ    4096
#define MD     256
#define KSPLIT 8
#define SCHUNK (SEQ / KSPLIT)   // 512
#define BK     64
#define NSTEP  (SCHUNK / BK)    // 8

__device__ __forceinline__ ushort bf_hi(float x) {
    // truncation split: hi keeps top 8 mantissa bits; residual captured by lo
    return (ushort)(__float_as_uint(x) >> 16);
}
__device__ __forceinline__ float bf_f(ushort u) {
    return __uint_as_float(((uint)u) << 16);
}

__global__ __launch_bounds__(1024) void opm_kernel(const float* __restrict__ A,
                                                   const float* __restrict__ B,
                                                   float* __restrict__ out) {
    const int bid = blockIdx.x;
    const int b   = bid >> 3;   // batch
    const int kc  = bid & 7;    // K-chunk
    const int tid = threadIdx.x;

    // 4 x [256][64] bf16 = 128 KB
    __shared__ ushort ldsAh[256 * 64];
    __shared__ ushort ldsAl[256 * 64];
    __shared__ ushort ldsBh[256 * 64];
    __shared__ ushort ldsBl[256 * 64];

    // ---- staging role: threads 0..511 stage A, 512..1023 stage B ----
    const int  t      = tid & 511;
    const int  sblk   = t >> 6;      // 0..7  : s-block of 8 rows
    const int  lane64 = t & 63;      // float4 column index (m4)
    const bool isB    = tid >= 512;
    const fvec4* gsrc = reinterpret_cast<const fvec4*>(isB ? B : A)
                        + (size_t)b * (SEQ * MD / 4);
    ushort* H = isB ? ldsBh : ldsAh;
    ushort* L = isB ? ldsBl : ldsAl;
    const int s_base = kc * SCHUNK;

    // ---- compute role: 16 waves in 4x4 grid, wave tile 64x64 ----
    const int w   = tid >> 6;
    const int wm  = w >> 2, wn = w & 3;
    const int l   = tid & 63;
    const int r16 = l & 15, g = l >> 4;

    f32x4 acc[4][4] = {};

    fvec4 RA[8], RB[8];

    // prologue: issue step-0 loads
    {
        const int s0 = s_base + sblk * 8;
#pragma unroll
        for (int i = 0; i < 8; ++i)
            RA[i] = gsrc[(s0 + i) * (MD / 4) + lane64];
    }

    auto step = [&](fvec4 (&RC)[8], fvec4 (&RN)[8], int st) {
        // 1) issue next tile's global loads (in flight across barriers/compute)
        if (st + 1 < NSTEP) {
            const int s0 = s_base + (st + 1) * BK + sblk * 8;
#pragma unroll
            for (int i = 0; i < 8; ++i)
                RN[i] = gsrc[(s0 + i) * (MD / 4) + lane64];
        }
        // 2) convert current tile: fp32 -> bf16 hi/lo, transposed vectors
        bf16x8 hv[4], lv[4];
#pragma unroll
        for (int c = 0; c < 4; ++c) {
#pragma unroll
            for (int i = 0; i < 8; ++i) {
                float  x  = RC[i][c];
                ushort hb = bf_hi(x);
                float  lo = x - bf_f(hb);
                hv[c][i] = (short)hb;
                lv[c][i] = (short)bf_hi(lo);
            }
        }
        // 3) B1: all waves done reading LDS from previous step
        __builtin_amdgcn_s_barrier();
        // 4) transposed swizzled LDS writes: row m = 4*lane64+c, slot = sblk
#pragma unroll
        for (int c = 0; c < 4; ++c) {
            const int m  = lane64 * 4 + c;
            const int so = ((sblk ^ ((m >> 1) & 7)) * 8);
            *reinterpret_cast<bf16x8*>(&H[m * 64 + so]) = hv[c];
            *reinterpret_cast<bf16x8*>(&L[m * 64 + so]) = lv[c];
        }
        asm volatile("s_waitcnt lgkmcnt(0)" ::: "memory");
        // 5) B2: tile visible to all waves
        __builtin_amdgcn_s_barrier();
        // 6) MFMA compute: 2 k-steps of 32, 4x4 frags, 3-way split
#pragma unroll
        for (int kk = 0; kk < 2; ++kk) {
            bf16x8 ah[4], al[4], bh[4], bl[4];
#pragma unroll
            for (int f = 0; f < 4; ++f) {
                const int ra = wm * 64 + f * 16 + r16;
                const int sa = ((kk * 4 + g) ^ ((ra >> 1) & 7)) * 8;
                ah[f] = *reinterpret_cast<const bf16x8*>(&ldsAh[ra * 64 + sa]);
                al[f] = *reinterpret_cast<const bf16x8*>(&ldsAl[ra * 64 + sa]);
                const int rb = wn * 64 + f * 16 + r16;
                const int sb = ((kk * 4 + g) ^ ((rb >> 1) & 7)) * 8;
                bh[f] = *reinterpret_cast<const bf16x8*>(&ldsBh[rb * 64 + sb]);
                bl[f] = *reinterpret_cast<const bf16x8*>(&ldsBl[rb * 64 + sb]);
            }
#pragma unroll
            for (int fm = 0; fm < 4; ++fm) {
#pragma unroll
                for (int fn = 0; fn < 4; ++fn) {
                    acc[fm][fn] = __builtin_amdgcn_mfma_f32_16x16x32_bf16(
                        ah[fm], bh[fn], acc[fm][fn], 0, 0, 0);
                    acc[fm][fn] = __builtin_amdgcn_mfma_f32_16x16x32_bf16(
                        ah[fm], bl[fn], acc[fm][fn], 0, 0, 0);
                    acc[fm][fn] = __builtin_amdgcn_mfma_f32_16x16x32_bf16(
                        al[fm], bh[fn], acc[fm][fn], 0, 0, 0);
                }
            }
        }
    };

    for (int half = 0; half < NSTEP / 2; ++half) {
        step(RA, RB, 2 * half);
        step(RB, RA, 2 * half + 1);
    }

    // epilogue: scale + atomic accumulate (8 K-chunk blocks per output)
    const float inv = 1.0f / (float)SEQ;
    float* ob = out + (size_t)b * (MD * MD);
#pragma unroll
    for (int fm = 0; fm < 4; ++fm) {
#pragma unroll
        for (int fn = 0; fn < 4; ++fn) {
#pragma unroll
            for (int r = 0; r < 4; ++r) {
                const int row = wm * 64 + fm * 16 + g * 4 + r;
                const int col = wn * 64 + fn * 16 + r16;
                unsafeAtomicAdd(&ob[row * MD + col], acc[fm][fn][r] * inv);
            }
        }
    }
}

extern "C" void kernel_launch(void* const* d_in, const int* in_sizes, int n_in,
                              void* d_out, int out_size, void* d_ws, size_t ws_size,
                              hipStream_t stream) {
    const float* A = (const float*)d_in[0];
    const float* B = (const float*)d_in[1];
    float* out     = (float*)d_out;

    // zero output (harness poisons with 0xAA); atomics accumulate into it
    hipMemsetAsync(d_out, 0, (size_t)out_size * sizeof(float), stream);

    dim3 grid(32 * KSPLIT);   // 256 blocks = 1 per CU
    dim3 block(1024);         // 16 waves
    hipLaunchKernelGGL(opm_kernel, grid, block, 0, stream, A, B, out);
}

// Round 2
// 298.446 us; speedup vs baseline: 1.3553x; 1.3553x over previous
//
#include <hip/hip_runtime.h>

// OuterProductMean: C[b] = A[b]^T @ B[b] / S ; A,B (32,4096,256) fp32.
// bf16 hi/lo split GEMM. Interleaved-packed LDS groups [hi(4k), lo(4k)]:
//   mfma(a, b)        -> sum hi*hi + lo*lo   (slots align)
//   mfma(swap(a), b)  -> sum lo*hi + hi*lo   (cross terms)
// 2 MFMAs per 16 real k, full 4-term product => ~2^-15 rel accuracy.
// Block 256 thr (4 waves 2x2), tile 128x128, BK=64, KSPLIT=4 -> 512 blocks
// (2/CU, launch_bounds(256,2) -> 256 VGPR budget, no spills).
// Sibling tiles of one (batch,kc) share XCD (bid%8) for L2 panel reuse.

typedef __attribute__((ext_vector_type(8))) short  bf16x8;
typedef __attribute__((ext_vector_type(4))) float  f32x4;
typedef __attribute__((ext_vector_type(8))) ushort u16x8;
typedef __attribute__((ext_vector_type(4))) float  fvec4;

#define SEQ    4096
#define MD     256
#define KSPLIT 4
#define SCHUNK (SEQ / KSPLIT)   // 1024
#define BK     64
#define NSTEP  (SCHUNK / BK)    // 16

#define FENCE() asm volatile("" ::: "memory")

__device__ __forceinline__ int swz(int m) { return ((m >> 2) ^ (m << 1)) & 15; }

__global__ __launch_bounds__(256, 2) void opm_kernel(const float* __restrict__ A,
                                                     const float* __restrict__ B,
                                                     float* __restrict__ out) {
    const int bid = blockIdx.x;
    const int grp = bid & 127;       // (batch, kc) -> bid%8 fixes XCD per group
    const int til = bid >> 7;        // (mt, nt) sibling index
    const int b   = grp >> 2;
    const int kc  = grp & 3;
    const int mt  = til >> 1;
    const int nt  = til & 1;
    const int tid = threadIdx.x;

    // [m 0..127][16 groups][8 ushort: hi0..3, lo0..3] ; 32 KB each
    __shared__ ushort ldsA[128 * 128];
    __shared__ ushort ldsB[128 * 128];

    // ---- staging addressing ----
    const int c4 = tid & 31;   // float4 column within 128-wide tile
    const int sb = tid >> 5;   // 0..7
    const fvec4* gA = (const fvec4*)A + (size_t)b * (SEQ * MD / 4) + mt * 32 + c4;
    const fvec4* gB = (const fvec4*)B + (size_t)b * (SEQ * MD / 4) + nt * 32 + c4;
    const int s0 = kc * SCHUNK;

    // ---- compute addressing ----
    const int lane = tid & 63;
    const int w    = tid >> 6;
    const int wm   = w >> 1, wn = w & 1;
    const int r16  = lane & 15, gq = lane >> 4;

    int mAr[4], nBr[4], f3a[4], f3b[4];
#pragma unroll
    for (int f = 0; f < 4; ++f) {
        mAr[f] = wm * 64 + f * 16 + r16;
        nBr[f] = wn * 64 + f * 16 + r16;
        f3a[f] = swz(mAr[f]);
        f3b[f] = swz(nBr[f]);
    }

    f32x4 acc[4][4] = {};
    fvec4 ra[2][4], rb[2][4];

    auto issue = [&](int st) {
        const int srow = s0 + st * BK;
#pragma unroll
        for (int it = 0; it < 2; ++it) {
            const int sl = (sb + 8 * it) * 4;
#pragma unroll
            for (int r = 0; r < 4; ++r) {
                ra[it][r] = gA[(size_t)(srow + sl + r) * (MD / 4)];
                rb[it][r] = gB[(size_t)(srow + sl + r) * (MD / 4)];
            }
        }
    };

    auto convert_write = [&]() {
#pragma unroll
        for (int it = 0; it < 2; ++it) {
            const int lg = sb + 8 * it;   // logical 4-k group 0..15
#pragma unroll
            for (int j = 0; j < 4; ++j) {
                const int m = c4 * 4 + j;
                u16x8 va, vb;
#pragma unroll
                for (int r = 0; r < 4; ++r) {
                    const float xa = ra[it][r][j];
                    const uint  ua = __float_as_uint(xa);
                    const float la = xa - __uint_as_float(ua & 0xffff0000u);
                    va[r]     = (ushort)(ua >> 16);
                    va[4 + r] = (ushort)(__float_as_uint(la) >> 16);
                    const float xb = rb[it][r][j];
                    const uint  ub = __float_as_uint(xb);
                    const float lb = xb - __uint_as_float(ub & 0xffff0000u);
                    vb[r]     = (ushort)(ub >> 16);
                    vb[4 + r] = (ushort)(__float_as_uint(lb) >> 16);
                }
                const int idx = m * 128 + ((lg ^ swz(m)) * 8);
                *(u16x8*)&ldsA[idx] = va;
                *(u16x8*)&ldsB[idx] = vb;
            }
        }
    };

    issue(0);

    for (int st = 0; st < NSTEP; ++st) {
        convert_write();              // waits vmcnt via reg deps
        if (st + 1 < NSTEP) issue(st + 1);   // prefetch flies across barriers
        FENCE();
        asm volatile("s_waitcnt lgkmcnt(0)" ::: "memory");
        __builtin_amdgcn_s_barrier(); // writes visible to all waves
        FENCE();

#pragma unroll
        for (int q = 0; q < 4; ++q) {  // 16 real k per chunk
            bf16x8 bq[4];
#pragma unroll
            for (int fn = 0; fn < 4; ++fn) {
                const int pg = (q * 4 + gq) ^ f3b[fn];
                bq[fn] = *(const bf16x8*)&ldsB[nBr[fn] * 128 + pg * 8];
            }
#pragma unroll
            for (int fm = 0; fm < 4; ++fm) {
                const int pg = (q * 4 + gq) ^ f3a[fm];
                bf16x8 a   = *(const bf16x8*)&ldsA[mAr[fm] * 128 + pg * 8];
                bf16x8 asw = __builtin_shufflevector(a, a, 4, 5, 6, 7, 0, 1, 2, 3);
#pragma unroll
                for (int fn = 0; fn < 4; ++fn) {
                    acc[fm][fn] = __builtin_amdgcn_mfma_f32_16x16x32_bf16(
                        a, bq[fn], acc[fm][fn], 0, 0, 0);      // hh + ll
                    acc[fm][fn] = __builtin_amdgcn_mfma_f32_16x16x32_bf16(
                        asw, bq[fn], acc[fm][fn], 0, 0, 0);    // lh + hl
                }
            }
        }

        FENCE();
        __builtin_amdgcn_s_barrier(); // all reads done before next overwrite
        FENCE();
    }

    // epilogue: scale + atomic accumulate (KSPLIT=4 contributors per output)
    const float inv = 1.0f / (float)SEQ;
    float* ob = out + (size_t)b * (MD * MD) + (size_t)(mt * 128) * MD + nt * 128;
#pragma unroll
    for (int fm = 0; fm < 4; ++fm) {
#pragma unroll
        for (int fn = 0; fn < 4; ++fn) {
#pragma unroll
            for (int r = 0; r < 4; ++r) {
                const int row = wm * 64 + fm * 16 + gq * 4 + r;
                const int col = wn * 64 + fn * 16 + r16;
                unsafeAtomicAdd(&ob[row * MD + col], acc[fm][fn][r] * inv);
            }
        }
    }
}

extern "C" void kernel_launch(void* const* d_in, const int* in_sizes, int n_in,
                              void* d_out, int out_size, void* d_ws, size_t ws_size,
                              hipStream_t stream) {
    const float* A = (const float*)d_in[0];
    const float* B = (const float*)d_in[1];
    float* out     = (float*)d_out;

    hipMemsetAsync(d_out, 0, (size_t)out_size * sizeof(float), stream);

    dim3 grid(512);    // 128 (b,kc) groups x 4 sibling tiles; 2 blocks/CU
    dim3 block(256);   // 4 waves
    hipLaunchKernelGGL(opm_kernel, grid, block, 0, stream, A, B, out);
}